// Round 7
// baseline (131.459 us; speedup 1.0000x reference)
//
#include <hip/hip_runtime.h>

// LRMU scan collapsed to out = U_rev^T @ P with P[j] = b·A^j via log-doubling.
// R7 = R6's validated data scheme (sc1 write-once stores + normal cached
// loads; 8 distinct A-power buffers; single persistent kernel) with the
// barrier reduced from 2 cross-MALL hops to 1: arrival = one sc1 atomicAdd
// per block onto 8 counter lines (32 RMWs/line, pipelined), detect = lanes
// 0..7 of every block poll the 8 counters with s_sleep backoff. Barrier-cost
// ledger: R2/R3 fences ~22-45us; R5 poll-DoS ~9.4us; R6 2-hop ~6.3us;
// predicted here ~1.5-2us.

#define SEQ_T 256
#define DIM 128
#define ORD 256
#define BMROWS 2048

// float offsets into ws (write-once buffers, guard gaps)
#define OFF_U 0                                  // U[t][bm]: 256*2048
#define OFF_P (OFF_U + SEQ_T * BMROWS)           // P[j][o]: 256*256
#define APSTRIDE (ORD * ORD + 2048)
#define OFF_AP (OFF_P + ORD * ORD + 2048)        // AP[j]=A^(2^(j+1))
#define OFF_FLAGS (OFF_AP + 7 * APSTRIDE + 2048) // 8 counters, 64B apart

#define LD_A(p) \
  __hip_atomic_load((p), __ATOMIC_RELAXED, __HIP_MEMORY_SCOPE_AGENT)
#define ST_A(p, v) \
  __hip_atomic_store((p), (v), __ATOMIC_RELAXED, __HIP_MEMORY_SCOPE_AGENT)

// Single-hop fence-free grid barrier (256 blocks): each block bumps one of
// 8 counter lines; every block's wave 0 (lanes 0..7) polls all 8 counters.
// Proceed when each counter hits 32*step. No gen hop, no __threadfence.
__device__ __forceinline__ void gbar(unsigned* cnts, unsigned target) {
  asm volatile("s_waitcnt vmcnt(0)" ::: "memory");  // this wave's sc1 drained
  __syncthreads();  // all waves of block drained
  const int tid = threadIdx.x;
  if (tid == 0)
    (void)__hip_atomic_fetch_add(&cnts[(blockIdx.x & 7) * 16], 1u,
                                 __ATOMIC_RELAXED, __HIP_MEMORY_SCOPE_AGENT);
  if (tid < 8) {
    while (LD_A(&cnts[tid * 16]) < target) __builtin_amdgcn_s_sleep(4);
  }
  __syncthreads();
}

__global__ __launch_bounds__(256) void lrmu_all(
    const float* __restrict__ x, const float* __restrict__ K,
    const float* __restrict__ A, const float* __restrict__ Bm,
    float* __restrict__ out, float* __restrict__ ws) {
  __shared__ __align__(16) float Slds[ORD * 64];  // 64 KB: S col-slice / out red
  __shared__ __align__(16) float lsb[2048];       // 8 KB: chain left rows / us
  __shared__ __align__(16) float redb[4 * 320];   // 5 KB: chain wave partials
  float* U = ws + OFF_U;
  float* P = ws + OFF_P;
  unsigned* cnts = (unsigned*)(ws + OFF_FLAGS);
  const int blk = blockIdx.x, tid = threadIdx.x;

  // ---------- U phase: U[t][bm] = sum_d x[b][t][d] * K[d][m] ----------
  {
    int b = blk >> 4, tc = blk & 15;
    float* xs = Slds;
    for (int idx = tid; idx < 16 * DIM; idx += 256)
      xs[idx] = x[(b * SEQ_T + tc * 16) * DIM + idx];
    __syncthreads();
    int m = tid & 127, th = tid >> 7;
    float acc[8] = {};
#pragma unroll 8
    for (int d = 0; d < DIM; ++d) {
      float kv = K[d * DIM + m];  // coalesced, L2-resident
#pragma unroll
      for (int r = 0; r < 8; ++r)
        acc[r] = fmaf(xs[(th * 8 + r) * DIM + d], kv, acc[r]);
    }
#pragma unroll
    for (int r = 0; r < 8; ++r)  // sc1: read cross-XCD at out phase
      ST_A(&U[(tc * 16 + th * 8 + r) * BMROWS + b * DIM + m], acc[r]);
    if (blk == 0) ST_A(&P[tid], Bm[tid]);  // P[0][:] = b (first read: k=1)
    __syncthreads();  // before Slds reuse in chain
  }

  // ---------- chain: step k reads S=A^(2^k), writes S^2 and P doubling ----
  const int rg = blk >> 2, cg = blk & 3;
  const int lane = tid & 63, q = tid >> 6;
  const int ir = lane >> 4, c4 = (lane & 15) * 4;
  for (int k = 0; k < 8; ++k) {
    const float* S = (k == 0) ? A : (ws + OFF_AP + (k - 1) * APSTRIDE);
    float* Snew = ws + OFF_AP + ((k < 7) ? k : 6) * APSTRIDE;  // unused k=7
    const int half = 1 << k;
    const int nsq = (k < 7) ? 4 : 0;
    const int ndb = (k == 7) ? 2 : (rg < half ? 1 : 0);
    const int nrows = nsq + ndb;

    // stage left rows into lsb[5][256]; zero-pad unused
#pragma unroll
    for (int s = 0; s < 5; ++s) {
      float v = 0.f;
      if (s < nsq) {
        v = S[(4 * rg + s) * ORD + tid];
      } else if (s - nsq < ndb) {
        int d = rg + 64 * (s - nsq);
        v = (k == 0) ? Bm[tid] : P[d * ORD + tid];  // write-once P rows
      }
      lsb[s * ORD + tid] = v;
    }
    // stage right slice S[:, 64cg..+64) into Slds[256][64] via float4
#pragma unroll
    for (int j = 0; j < 16; ++j) {
      int f = tid + 256 * j;
      int i = f >> 4, cc = (f & 15) * 4;
      *(float4*)&Slds[i * 64 + cc] =
          *(const float4*)&S[i * ORD + cg * 64 + cc];
    }
    __syncthreads();

    // wave q covers K-chunk [64q,64q+64); lane = (ir K-subsplit, c4 cols)
    float acc[5][4] = {};
#pragma unroll 4
    for (int ii = 0; ii < 16; ++ii) {
      int i = q * 64 + 4 * ii + ir;
      float4 sv = *(const float4*)&Slds[i * 64 + c4];  // b128 LDS
#pragma unroll
      for (int s = 0; s < 5; ++s) {
        float lv = lsb[s * ORD + i];  // broadcast
        acc[s][0] = fmaf(lv, sv.x, acc[s][0]);
        acc[s][1] = fmaf(lv, sv.y, acc[s][1]);
        acc[s][2] = fmaf(lv, sv.z, acc[s][2]);
        acc[s][3] = fmaf(lv, sv.w, acc[s][3]);
      }
    }
#pragma unroll
    for (int s = 0; s < 5; ++s)
#pragma unroll
      for (int w = 0; w < 4; ++w) {
        acc[s][w] += __shfl_xor(acc[s][w], 16);
        acc[s][w] += __shfl_xor(acc[s][w], 32);
      }
    if (ir == 0) {
#pragma unroll
      for (int s = 0; s < 5; ++s)
        *(float4*)&redb[q * 320 + s * 64 + c4] =
            make_float4(acc[s][0], acc[s][1], acc[s][2], acc[s][3]);
    }
    __syncthreads();
    for (int o = tid; o < 320; o += 256) {
      int s = o >> 6, c = o & 63;
      if (s < nrows) {
        float sum = redb[o] + redb[320 + o] + redb[640 + o] + redb[960 + o];
        if (s < nsq) {
          ST_A(&Snew[(4 * rg + s) * ORD + cg * 64 + c], sum);
        } else {
          int d = rg + 64 * (s - nsq);
          ST_A(&P[(half + d) * ORD + cg * 64 + c], sum);
        }
      }
    }
    gbar(cnts, (unsigned)(32 * (k + 1)));
  }

  // ---------- out: out[bm][o] = sum_t U[t][bm] * P[255-t][o] ----------
  {
    float* us = lsb;     // [256][8]
    float* redo = Slds;  // [4][8][256] wave partials
    int bm0 = blk * 8;
    for (int idx = tid; idx < SEQ_T * 8; idx += 256) {
      int t = idx >> 3, r = idx & 7;
      us[idx] = U[t * BMROWS + bm0 + r];  // normal load: first touch of U
    }
    __syncthreads();
    int c4o = lane * 4, qo = q;  // lane: 4 cols; wave: 64 t's
    float ao[8][4] = {};
#pragma unroll 4
    for (int tt = 0; tt < 64; ++tt) {
      int t = qo * 64 + tt;
      float4 pv = *(const float4*)&P[(SEQ_T - 1 - t) * ORD + c4o];  // L2-hot
      float4 u0 = *(const float4*)&us[t * 8];  // LDS broadcast
      float4 u1 = *(const float4*)&us[t * 8 + 4];
      float uv[8] = {u0.x, u0.y, u0.z, u0.w, u1.x, u1.y, u1.z, u1.w};
      float pw[4] = {pv.x, pv.y, pv.z, pv.w};
#pragma unroll
      for (int r = 0; r < 8; ++r)
#pragma unroll
        for (int w = 0; w < 4; ++w)
          ao[r][w] = fmaf(uv[r], pw[w], ao[r][w]);
    }
#pragma unroll
    for (int r = 0; r < 8; ++r)
      *(float4*)&redo[qo * 2048 + r * 256 + c4o] =
          make_float4(ao[r][0], ao[r][1], ao[r][2], ao[r][3]);
    __syncthreads();
#pragma unroll
    for (int j = 0; j < 8; ++j) {
      int o = tid + 256 * j;  // o = r*256 + c
      float s = redo[o] + redo[2048 + o] + redo[4096 + o] + redo[6144 + o];
      out[bm0 * ORD + o] = s;  // kernel-end release flushes
    }
  }
}

extern "C" void kernel_launch(void* const* d_in, const int* in_sizes, int n_in,
                              void* d_out, int out_size, void* d_ws,
                              size_t ws_size, hipStream_t stream) {
  const float* x = (const float*)d_in[0];   // (16,256,128)
  const float* K = (const float*)d_in[1];   // (128,128)
  const float* A = (const float*)d_in[2];   // (256,256)
  const float* Bm = (const float*)d_in[3];  // (256,)
  float* out = (float*)d_out;               // (16, 32768)
  float* ws = (float*)d_ws;

  // zero barrier counters (ws re-poisoned 0xAA before every timed call)
  hipMemsetAsync(ws + OFF_FLAGS, 0, 2048, stream);
  lrmu_all<<<256, 256, 0, stream>>>(x, K, A, Bm, out, ws);
}

// Round 8
// 130.616 us; speedup vs baseline: 1.0064x; 1.0064x over previous
//
#include <hip/hip_runtime.h>

// LRMU scan collapsed to out = U_rev^T @ P with P[j] = b·A^j via log-doubling.
// R8 = R6 (best: 62us) + two changes:
//  (1) barrier release fanned out to 8 gen lines (waiter polls gen[blk&7],
//      ~32 pollers/line, s_sleep(3)) -- R6 had 255 pollers at s_sleep(1) on
//      ONE line, delaying the release store's visibility; R7 proved mixing
//      arrivals and polls on the same lines is even worse.
//  (2) k=7 doubling removed: out = H + G*A^128 where
//      H = sum_{j<128} U[255-j] (x) P[j],  G = sum_{j<128} U[127-j] (x) P[j].
//      G*A^128 is block-local (no barrier); chain is 7 steps / 7 barriers.
// Data scheme unchanged (validated R5-R7): sc1 write-once stores + normal
// cached first-touch loads; distinct A-power buffers; no __threadfence.

#define SEQ_T 256
#define DIM 128
#define ORD 256
#define BMROWS 2048

// float offsets into ws (write-once buffers, guard gaps)
#define OFF_U 0                                  // U[t][bm]: 256*2048
#define OFF_P (OFF_U + SEQ_T * BMROWS)           // P[j][o]: rows 0..127 used
#define APSTRIDE (ORD * ORD + 2048)
#define OFF_AP (OFF_P + ORD * ORD + 2048)        // AP[k]=A^(2^(k+1)), k=0..6
#define OFF_FLAGS (OFF_AP + 7 * APSTRIDE + 2048) // 256 flags + 8 gen lines

#define LD_A(p) \
  __hip_atomic_load((p), __ATOMIC_RELAXED, __HIP_MEMORY_SCOPE_AGENT)
#define ST_A(p, v) \
  __hip_atomic_store((p), (v), __ATOMIC_RELAXED, __HIP_MEMORY_SCOPE_AGENT)

// Fence-free 2-hop grid barrier, de-pressurized: arrival flags (16 lines) are
// never the polled lines; release = 8 gen words so each carries ~32 pollers.
__device__ __forceinline__ void gbar(unsigned* flags, unsigned target) {
  asm volatile("s_waitcnt vmcnt(0)" ::: "memory");  // drain this wave's sc1 st
  __syncthreads();  // all waves of the block drained
  const int tid = threadIdx.x;
  if (blockIdx.x == 0) {
    if (tid == 0) ST_A(&flags[0], target);
    while (LD_A(&flags[tid]) < target) __builtin_amdgcn_s_sleep(2);
    __syncthreads();  // all 256 flags seen
    if (tid < 8) ST_A(&flags[256 + tid * 16], target);  // 8-way release
  } else {
    if (tid == 0) {
      ST_A(&flags[blockIdx.x], target);
      unsigned* g = &flags[256 + (blockIdx.x & 7) * 16];
      while (LD_A(g) < target) __builtin_amdgcn_s_sleep(3);
    }
  }
  __syncthreads();
}

__global__ __launch_bounds__(256) void lrmu_all(
    const float* __restrict__ x, const float* __restrict__ K,
    const float* __restrict__ A, const float* __restrict__ Bm,
    float* __restrict__ out, float* __restrict__ ws) {
  __shared__ __align__(16) float Slds[ORD * 64];  // 64 KB: S slice / out red
  __shared__ __align__(16) float lsb[2048];       // 8 KB: left rows / us / G
  __shared__ __align__(16) float redb[4 * 320];   // 5 KB: chain wave partials
  float* U = ws + OFF_U;
  float* P = ws + OFF_P;
  unsigned* flags = (unsigned*)(ws + OFF_FLAGS);
  const int blk = blockIdx.x, tid = threadIdx.x;

  // ---------- U phase: U[t][bm] = sum_d x[b][t][d] * K[d][m] ----------
  {
    int b = blk >> 4, tc = blk & 15;
    float* xs = Slds;
    for (int idx = tid; idx < 16 * DIM; idx += 256)
      xs[idx] = x[(b * SEQ_T + tc * 16) * DIM + idx];
    __syncthreads();
    int m = tid & 127, th = tid >> 7;
    float acc[8] = {};
#pragma unroll 8
    for (int d = 0; d < DIM; ++d) {
      float kv = K[d * DIM + m];  // coalesced, L2-resident
#pragma unroll
      for (int r = 0; r < 8; ++r)
        acc[r] = fmaf(xs[(th * 8 + r) * DIM + d], kv, acc[r]);
    }
#pragma unroll
    for (int r = 0; r < 8; ++r)  // sc1: read cross-XCD at out phase
      ST_A(&U[(tc * 16 + th * 8 + r) * BMROWS + b * DIM + m], acc[r]);
    if (blk == 0) ST_A(&P[tid], Bm[tid]);  // P[0][:] = b
    __syncthreads();  // before Slds reuse in chain
  }

  // ---------- chain: 7 steps. Step k reads S=A^(2^k); writes S^2 to AP[k]
  // and P[half+rg] = P[rg] @ S (rg < half = 2^k). ----------
  const int rg = blk >> 2, cg = blk & 3;
  const int lane = tid & 63, q = tid >> 6;
  const int ir = lane >> 4, c4 = (lane & 15) * 4;
  for (int k = 0; k < 7; ++k) {
    const float* S = (k == 0) ? A : (ws + OFF_AP + (k - 1) * APSTRIDE);
    float* Snew = ws + OFF_AP + k * APSTRIDE;
    const int half = 1 << k;
    const int ndb = (rg < half) ? 1 : 0;
    const int nrows = 4 + ndb;

    // stage left rows into lsb[5][256]: 4 squaring rows + optional P row
#pragma unroll
    for (int s = 0; s < 5; ++s) {
      float v = 0.f;
      if (s < 4) {
        v = S[(4 * rg + s) * ORD + tid];
      } else if (ndb) {
        v = (k == 0) ? Bm[tid] : P[rg * ORD + tid];  // write-once P rows
      }
      lsb[s * ORD + tid] = v;
    }
    // stage right slice S[:, 64cg..+64) into Slds[256][64] via float4
#pragma unroll
    for (int j = 0; j < 16; ++j) {
      int f = tid + 256 * j;
      int i = f >> 4, cc = (f & 15) * 4;
      *(float4*)&Slds[i * 64 + cc] =
          *(const float4*)&S[i * ORD + cg * 64 + cc];
    }
    __syncthreads();

    // wave q covers K-chunk [64q,64q+64); lane = (ir K-subsplit, c4 cols)
    float acc[5][4] = {};
#pragma unroll 4
    for (int ii = 0; ii < 16; ++ii) {
      int i = q * 64 + 4 * ii + ir;
      float4 sv = *(const float4*)&Slds[i * 64 + c4];  // b128 LDS
#pragma unroll
      for (int s = 0; s < 5; ++s) {
        float lv = lsb[s * ORD + i];  // broadcast
        acc[s][0] = fmaf(lv, sv.x, acc[s][0]);
        acc[s][1] = fmaf(lv, sv.y, acc[s][1]);
        acc[s][2] = fmaf(lv, sv.z, acc[s][2]);
        acc[s][3] = fmaf(lv, sv.w, acc[s][3]);
      }
    }
#pragma unroll
    for (int s = 0; s < 5; ++s)
#pragma unroll
      for (int w = 0; w < 4; ++w) {
        acc[s][w] += __shfl_xor(acc[s][w], 16);
        acc[s][w] += __shfl_xor(acc[s][w], 32);
      }
    if (ir == 0) {
#pragma unroll
      for (int s = 0; s < 5; ++s)
        *(float4*)&redb[q * 320 + s * 64 + c4] =
            make_float4(acc[s][0], acc[s][1], acc[s][2], acc[s][3]);
    }
    __syncthreads();
    for (int o = tid; o < 320; o += 256) {
      int s = o >> 6, c = o & 63;
      if (s < nrows) {
        float sum = redb[o] + redb[320 + o] + redb[640 + o] + redb[960 + o];
        if (s < 4) {
          ST_A(&Snew[(4 * rg + s) * ORD + cg * 64 + c], sum);
        } else {
          ST_A(&P[(half + rg) * ORD + cg * 64 + c], sum);
        }
      }
    }
    gbar(flags, (unsigned)(k + 1));
  }

  // ---------- out: out = H + G @ A^128,  H=sum_{j<128} U[255-j] (x) P[j],
  //                                       G=sum_{j<128} U[127-j] (x) P[j] ----
  {
    const float* S128 = ws + OFF_AP + 6 * APSTRIDE;
    float* us = lsb;     // [256][8]: us[t][r] = U[t][bm0+r]
    float* redo = Slds;  // [4][16][256] wave partials (64 KB)
    int bm0 = blk * 8;
    for (int idx = tid; idx < SEQ_T * 8; idx += 256) {
      int t = idx >> 3, r = idx & 7;
      us[idx] = U[t * BMROWS + bm0 + r];  // normal load: first touch of U
    }
    __syncthreads();
    int c4o = lane * 4;  // lane: 4 P-cols; wave q: j in [32q, 32q+32)
    float acc[8][4];
    // --- H pass ---
#pragma unroll
    for (int r = 0; r < 8; ++r)
#pragma unroll
      for (int w = 0; w < 4; ++w) acc[r][w] = 0.f;
#pragma unroll 4
    for (int jj = 0; jj < 32; ++jj) {
      int j = q * 32 + jj;
      float4 pv = *(const float4*)&P[j * ORD + c4o];  // L2-hot
      float4 u0 = *(const float4*)&us[(255 - j) * 8];
      float4 u1 = *(const float4*)&us[(255 - j) * 8 + 4];
      float uv[8] = {u0.x, u0.y, u0.z, u0.w, u1.x, u1.y, u1.z, u1.w};
      float pw[4] = {pv.x, pv.y, pv.z, pv.w};
#pragma unroll
      for (int r = 0; r < 8; ++r)
#pragma unroll
        for (int w = 0; w < 4; ++w)
          acc[r][w] = fmaf(uv[r], pw[w], acc[r][w]);
    }
#pragma unroll
    for (int r = 0; r < 8; ++r)
      *(float4*)&redo[q * 4096 + r * 256 + c4o] =
          make_float4(acc[r][0], acc[r][1], acc[r][2], acc[r][3]);
    // --- G pass ---
#pragma unroll
    for (int r = 0; r < 8; ++r)
#pragma unroll
      for (int w = 0; w < 4; ++w) acc[r][w] = 0.f;
#pragma unroll 4
    for (int jj = 0; jj < 32; ++jj) {
      int j = q * 32 + jj;
      float4 pv = *(const float4*)&P[j * ORD + c4o];
      float4 u0 = *(const float4*)&us[(127 - j) * 8];
      float4 u1 = *(const float4*)&us[(127 - j) * 8 + 4];
      float uv[8] = {u0.x, u0.y, u0.z, u0.w, u1.x, u1.y, u1.z, u1.w};
      float pw[4] = {pv.x, pv.y, pv.z, pv.w};
#pragma unroll
      for (int r = 0; r < 8; ++r)
#pragma unroll
        for (int w = 0; w < 4; ++w)
          acc[r][w] = fmaf(uv[r], pw[w], acc[r][w]);
    }
#pragma unroll
    for (int r = 0; r < 8; ++r)
      *(float4*)&redo[q * 4096 + (8 + r) * 256 + c4o] =
          make_float4(acc[r][0], acc[r][1], acc[r][2], acc[r][3]);
    __syncthreads();

    // reduce: H rows into registers (col c), G rows into lsb (us is dead)
    int c = tid;
    float hreg[8];
#pragma unroll
    for (int r = 0; r < 8; ++r)
      hreg[r] = redo[r * 256 + c] + redo[4096 + r * 256 + c] +
                redo[8192 + r * 256 + c] + redo[12288 + r * 256 + c];
    __syncthreads();  // everyone done reading us? (us dead since H/G passes)
#pragma unroll
    for (int r = 0; r < 8; ++r)
      lsb[r * 256 + c] = redo[(8 + r) * 256 + c] + redo[4096 + (8 + r) * 256 + c] +
                         redo[8192 + (8 + r) * 256 + c] +
                         redo[12288 + (8 + r) * 256 + c];
    __syncthreads();

    // out[bm0+r][c] = hreg[r] + sum_i G[r][i] * S128[i][c]
#pragma unroll 4
    for (int i = 0; i < 256; ++i) {
      float sv = S128[i * ORD + c];  // coalesced, L2-hot (same for all blocks)
#pragma unroll
      for (int r = 0; r < 8; ++r)
        hreg[r] = fmaf(lsb[r * 256 + i], sv, hreg[r]);  // LDS broadcast
    }
#pragma unroll
    for (int r = 0; r < 8; ++r) out[(bm0 + r) * ORD + c] = hreg[r];
  }
}

extern "C" void kernel_launch(void* const* d_in, const int* in_sizes, int n_in,
                              void* d_out, int out_size, void* d_ws,
                              size_t ws_size, hipStream_t stream) {
  const float* x = (const float*)d_in[0];   // (16,256,128)
  const float* K = (const float*)d_in[1];   // (128,128)
  const float* A = (const float*)d_in[2];   // (256,256)
  const float* Bm = (const float*)d_in[3];  // (256,)
  float* out = (float*)d_out;               // (16, 32768)
  float* ws = (float*)d_ws;

  // zero barrier flags + 8 gen lines (ws re-poisoned 0xAA every timed call)
  hipMemsetAsync(ws + OFF_FLAGS, 0, 2048, stream);
  lrmu_all<<<256, 256, 0, stream>>>(x, K, A, Bm, out, ws);
}

// Round 9
// 123.708 us; speedup vs baseline: 1.0627x; 1.0558x over previous
//
#include <hip/hip_runtime.h>

// LRMU scan collapsed to out = H + G@A^128, H = sum_{j<128} U[255-j] (x) P[j],
// G = sum_{j<128} U[127-j] (x) P[j], P[j] = b·A^j via 7-step log-doubling.
// R9 = R8 with: (1) barrier reverted to R6-exact (measured best: arrival
// lines separate from the single polled gen line, s_sleep(1)) but split into
// arrive/wait halves; (2) H/G accumulation SHADOWED into the barrier wait --
// after arriving at barrier k+1, each block accumulates P rows [2^(k-1),2^k)
// (finalized by barrier k, safe) into per-thread H/G registers; (3) Horner
// epilogue vectorized: G transposed in LDS (stride 12, b128-aligned),
// team-split i-range, float4 everywhere.
// Data scheme unchanged (validated R5-R8): sc1 write-once stores + normal
// cached first-touch loads; distinct A-power buffers; no __threadfence.

#define SEQ_T 256
#define DIM 128
#define ORD 256
#define BMROWS 2048

// float offsets into ws (write-once buffers, guard gaps)
#define OFF_U 0                                  // U[t][bm]: 256*2048
#define OFF_P (OFF_U + SEQ_T * BMROWS)           // P[j][o]: rows 0..127 used
#define APSTRIDE (ORD * ORD + 2048)
#define OFF_AP (OFF_P + ORD * ORD + 2048)        // AP[k]=A^(2^(k+1)), k=0..6
#define OFF_FLAGS (OFF_AP + 7 * APSTRIDE + 2048) // 256 flags; gen at word 320

#define LD_A(p) \
  __hip_atomic_load((p), __ATOMIC_RELAXED, __HIP_MEMORY_SCOPE_AGENT)
#define ST_A(p, v) \
  __hip_atomic_store((p), (v), __ATOMIC_RELAXED, __HIP_MEMORY_SCOPE_AGENT)

// R6-exact fence-free barrier, split so independent work can run between
// arrive and wait (inside the otherwise-dead barrier latency).
__device__ __forceinline__ void gbar_arrive(unsigned* flags, unsigned target) {
  asm volatile("s_waitcnt vmcnt(0)" ::: "memory");  // drain this wave's sc1 st
  __syncthreads();  // all waves of the block drained
  if (threadIdx.x == 0) ST_A(&flags[blockIdx.x], target);
}
__device__ __forceinline__ void gbar_wait(unsigned* flags, unsigned target) {
  const int tid = threadIdx.x;
  if (blockIdx.x == 0) {
    while (LD_A(&flags[tid]) < target) __builtin_amdgcn_s_sleep(1);
    __syncthreads();  // all 256 flags seen
    if (tid == 0) ST_A(&flags[320], target);  // gen word, separate line
  } else {
    if (tid == 0) {
      while (LD_A(&flags[320]) < target) __builtin_amdgcn_s_sleep(1);
    }
  }
  __syncthreads();
}

__global__ __launch_bounds__(256) void lrmu_all(
    const float* __restrict__ x, const float* __restrict__ K,
    const float* __restrict__ A, const float* __restrict__ Bm,
    float* __restrict__ out, float* __restrict__ ws) {
  __shared__ __align__(16) float Slds[ORD * 64];  // 64 KB: S slice / Gt+redo
  __shared__ __align__(16) float lsb[5 * ORD];    // 5 KB: chain left rows
  __shared__ __align__(16) float redb[4 * 320];   // 5 KB: chain wave partials
  __shared__ __align__(16) float us[SEQ_T * 8];   // 8 KB: U cols (persist)
  float* U = ws + OFF_U;
  float* P = ws + OFF_P;
  unsigned* flags = (unsigned*)(ws + OFF_FLAGS);
  const int blk = blockIdx.x, tid = threadIdx.x;
  const int bm0 = blk * 8;
  float hAcc[8] = {}, gAcc[8] = {};  // per-thread out accumulators (col=tid)

  // ---------- U phase: U[t][bm] = sum_d x[b][t][d] * K[d][m] ----------
  {
    int b = blk >> 4, tc = blk & 15;
    float* xs = Slds;
    for (int idx = tid; idx < 16 * DIM; idx += 256)
      xs[idx] = x[(b * SEQ_T + tc * 16) * DIM + idx];
    __syncthreads();
    int m = tid & 127, th = tid >> 7;
    float acc[8] = {};
#pragma unroll 8
    for (int d = 0; d < DIM; ++d) {
      float kv = K[d * DIM + m];  // coalesced, L2-resident
#pragma unroll
      for (int r = 0; r < 8; ++r)
        acc[r] = fmaf(xs[(th * 8 + r) * DIM + d], kv, acc[r]);
    }
#pragma unroll
    for (int r = 0; r < 8; ++r)  // sc1: read cross-XCD after barrier 1
      ST_A(&U[(tc * 16 + th * 8 + r) * BMROWS + b * DIM + m], acc[r]);
    if (blk == 0) ST_A(&P[tid], Bm[tid]);  // P[0][:] = b
    __syncthreads();  // before Slds reuse in chain
  }

  // ---------- chain: 7 steps. Step k reads S=A^(2^k); writes S^2 to AP[k]
  // and P[half+rg] = P[rg] @ S (rg < half = 2^k). H/G shadow work between
  // arrive and wait. ----------
  const int rg = blk >> 2, cg = blk & 3;
  const int lane = tid & 63, q = tid >> 6;
  const int ir = lane >> 4, c4 = (lane & 15) * 4;
  for (int k = 0; k < 7; ++k) {
    const float* S = (k == 0) ? A : (ws + OFF_AP + (k - 1) * APSTRIDE);
    float* Snew = ws + OFF_AP + k * APSTRIDE;
    const int half = 1 << k;
    const int ndb = (rg < half) ? 1 : 0;
    const int nrows = 4 + ndb;

    // stage left rows into lsb[5][256]: 4 squaring rows + optional P row
#pragma unroll
    for (int s = 0; s < 5; ++s) {
      float v = 0.f;
      if (s < 4) {
        v = S[(4 * rg + s) * ORD + tid];
      } else if (ndb) {
        v = (k == 0) ? Bm[tid] : P[rg * ORD + tid];  // write-once P rows
      }
      lsb[s * ORD + tid] = v;
    }
    // stage right slice S[:, 64cg..+64) into Slds[256][64] via float4
#pragma unroll
    for (int j = 0; j < 16; ++j) {
      int f = tid + 256 * j;
      int i = f >> 4, cc = (f & 15) * 4;
      *(float4*)&Slds[i * 64 + cc] =
          *(const float4*)&S[i * ORD + cg * 64 + cc];
    }
    __syncthreads();

    // wave q covers K-chunk [64q,64q+64); lane = (ir K-subsplit, c4 cols)
    float acc[5][4] = {};
#pragma unroll 4
    for (int ii = 0; ii < 16; ++ii) {
      int i = q * 64 + 4 * ii + ir;
      float4 sv = *(const float4*)&Slds[i * 64 + c4];  // b128 LDS
#pragma unroll
      for (int s = 0; s < 5; ++s) {
        float lv = lsb[s * ORD + i];  // broadcast
        acc[s][0] = fmaf(lv, sv.x, acc[s][0]);
        acc[s][1] = fmaf(lv, sv.y, acc[s][1]);
        acc[s][2] = fmaf(lv, sv.z, acc[s][2]);
        acc[s][3] = fmaf(lv, sv.w, acc[s][3]);
      }
    }
#pragma unroll
    for (int s = 0; s < 5; ++s)
#pragma unroll
      for (int w = 0; w < 4; ++w) {
        acc[s][w] += __shfl_xor(acc[s][w], 16);
        acc[s][w] += __shfl_xor(acc[s][w], 32);
      }
    if (ir == 0) {
#pragma unroll
      for (int s = 0; s < 5; ++s)
        *(float4*)&redb[q * 320 + s * 64 + c4] =
            make_float4(acc[s][0], acc[s][1], acc[s][2], acc[s][3]);
    }
    __syncthreads();
    for (int o = tid; o < 320; o += 256) {
      int s = o >> 6, c = o & 63;
      if (s < nrows) {
        float sum = redb[o] + redb[320 + o] + redb[640 + o] + redb[960 + o];
        if (s < 4) {
          ST_A(&Snew[(4 * rg + s) * ORD + cg * 64 + c], sum);
        } else {
          ST_A(&P[(half + rg) * ORD + cg * 64 + c], sum);
        }
      }
    }
    gbar_arrive(flags, (unsigned)(k + 1));

    // ---- shadow work inside the barrier wait: H/G terms for P rows
    // [2^(k-1), 2^k) -- finalized by barrier k (the PREVIOUS one). ----
    if (k >= 1) {
      if (k == 1) {  // U visible since barrier 1: stage this block's U cols
        for (int idx = tid; idx < SEQ_T * 8; idx += 256) {
          int t = idx >> 3, r = idx & 7;
          us[idx] = U[t * BMROWS + bm0 + r];
        }
        __syncthreads();
      }
      int jlo = (k == 1) ? 0 : (1 << (k - 1));
      int jhi = 1 << k;
      for (int j = jlo; j < jhi; ++j) {
        float pv = P[j * ORD + tid];  // coalesced, finalized row
        const float4 h0 = *(const float4*)&us[(255 - j) * 8];  // b128 bcast
        const float4 h1 = *(const float4*)&us[(255 - j) * 8 + 4];
        const float4 g0 = *(const float4*)&us[(127 - j) * 8];
        const float4 g1 = *(const float4*)&us[(127 - j) * 8 + 4];
        hAcc[0] = fmaf(h0.x, pv, hAcc[0]); hAcc[1] = fmaf(h0.y, pv, hAcc[1]);
        hAcc[2] = fmaf(h0.z, pv, hAcc[2]); hAcc[3] = fmaf(h0.w, pv, hAcc[3]);
        hAcc[4] = fmaf(h1.x, pv, hAcc[4]); hAcc[5] = fmaf(h1.y, pv, hAcc[5]);
        hAcc[6] = fmaf(h1.z, pv, hAcc[6]); hAcc[7] = fmaf(h1.w, pv, hAcc[7]);
        gAcc[0] = fmaf(g0.x, pv, gAcc[0]); gAcc[1] = fmaf(g0.y, pv, gAcc[1]);
        gAcc[2] = fmaf(g0.z, pv, gAcc[2]); gAcc[3] = fmaf(g0.w, pv, gAcc[3]);
        gAcc[4] = fmaf(g1.x, pv, gAcc[4]); gAcc[5] = fmaf(g1.y, pv, gAcc[5]);
        gAcc[6] = fmaf(g1.z, pv, gAcc[6]); gAcc[7] = fmaf(g1.w, pv, gAcc[7]);
      }
    }
    gbar_wait(flags, (unsigned)(k + 1));
  }

  // ---------- out phase: finish H/G (rows 64..127), then Horner ----------
  {
    // rows [64,128): finalized by barrier 7 (written at k=6)
    for (int j = 64; j < 128; ++j) {
      float pv = P[j * ORD + tid];
      const float4 h0 = *(const float4*)&us[(255 - j) * 8];
      const float4 h1 = *(const float4*)&us[(255 - j) * 8 + 4];
      const float4 g0 = *(const float4*)&us[(127 - j) * 8];
      const float4 g1 = *(const float4*)&us[(127 - j) * 8 + 4];
      hAcc[0] = fmaf(h0.x, pv, hAcc[0]); hAcc[1] = fmaf(h0.y, pv, hAcc[1]);
      hAcc[2] = fmaf(h0.z, pv, hAcc[2]); hAcc[3] = fmaf(h0.w, pv, hAcc[3]);
      hAcc[4] = fmaf(h1.x, pv, hAcc[4]); hAcc[5] = fmaf(h1.y, pv, hAcc[5]);
      hAcc[6] = fmaf(h1.z, pv, hAcc[6]); hAcc[7] = fmaf(h1.w, pv, hAcc[7]);
      gAcc[0] = fmaf(g0.x, pv, gAcc[0]); gAcc[1] = fmaf(g0.y, pv, gAcc[1]);
      gAcc[2] = fmaf(g0.z, pv, gAcc[2]); gAcc[3] = fmaf(g0.w, pv, gAcc[3]);
      gAcc[4] = fmaf(g1.x, pv, gAcc[4]); gAcc[5] = fmaf(g1.y, pv, gAcc[5]);
      gAcc[6] = fmaf(g1.z, pv, gAcc[6]); gAcc[7] = fmaf(g1.w, pv, gAcc[7]);
    }
    __syncthreads();  // Slds (chain S-slice) dead; reuse for Gt + redo

    // transpose G into LDS: Gt[i*12 + r] (stride 12 floats = 48 B, keeps
    // both float4 halves 16B-aligned; breaks pow-2 bank stride)
    float* Gt = Slds;          // 256*12 floats = 12 KB
    float* redo = Slds + 4096; // 4*8*256 floats = 32 KB
#pragma unroll
    for (int r = 0; r < 8; ++r) Gt[tid * 12 + r] = gAcc[r];
    __syncthreads();

    // Horner: GB[r][c] = sum_i G[r][i] * A128[i][c]; team-split over i
    const float* S128 = ws + OFF_AP + 6 * APSTRIDE;
    int team = tid >> 6, tc4 = (tid & 63) * 4;
    float hloc[8][4] = {};
#pragma unroll 4
    for (int ii = 0; ii < 64; ++ii) {
      int i = team * 64 + ii;
      float4 sv = *(const float4*)&S128[i * ORD + tc4];  // b128 coalesced
      float4 ga = *(const float4*)&Gt[i * 12];           // b128 broadcast
      float4 gb = *(const float4*)&Gt[i * 12 + 4];
      float gv[8] = {ga.x, ga.y, ga.z, ga.w, gb.x, gb.y, gb.z, gb.w};
#pragma unroll
      for (int r = 0; r < 8; ++r) {
        hloc[r][0] = fmaf(gv[r], sv.x, hloc[r][0]);
        hloc[r][1] = fmaf(gv[r], sv.y, hloc[r][1]);
        hloc[r][2] = fmaf(gv[r], sv.z, hloc[r][2]);
        hloc[r][3] = fmaf(gv[r], sv.w, hloc[r][3]);
      }
    }
#pragma unroll
    for (int r = 0; r < 8; ++r)
      *(float4*)&redo[team * 2048 + r * 256 + tc4] =
          make_float4(hloc[r][0], hloc[r][1], hloc[r][2], hloc[r][3]);
    __syncthreads();

    int c = tid;
#pragma unroll
    for (int r = 0; r < 8; ++r) {
      float gbv = redo[r * 256 + c] + redo[2048 + r * 256 + c] +
                  redo[4096 + r * 256 + c] + redo[6144 + r * 256 + c];
      out[(bm0 + r) * ORD + c] = hAcc[r] + gbv;
    }
  }
}

extern "C" void kernel_launch(void* const* d_in, const int* in_sizes, int n_in,
                              void* d_out, int out_size, void* d_ws,
                              size_t ws_size, hipStream_t stream) {
  const float* x = (const float*)d_in[0];   // (16,256,128)
  const float* K = (const float*)d_in[1];   // (128,128)
  const float* A = (const float*)d_in[2];   // (256,256)
  const float* Bm = (const float*)d_in[3];  // (256,)
  float* out = (float*)d_out;               // (16, 32768)
  float* ws = (float*)d_ws;

  // zero barrier flags + gen (ws re-poisoned 0xAA before every timed call)
  hipMemsetAsync(ws + OFF_FLAGS, 0, 2048, stream);
  lrmu_all<<<256, 256, 0, stream>>>(x, K, A, Bm, out, ws);
}